// Round 1
// baseline (708.180 us; speedup 1.0000x reference)
//
#include <hip/hip_runtime.h>
#include <hip/hip_bf16.h>

// Problem constants (fixed by the reference file).
constexpr int N_NODES = 20000;
constexpr int N_EDGES = 640000;
constexpr int D = 128;          // D_IN == D_OUT == 128

typedef float  f32x4  __attribute__((ext_vector_type(4)));
typedef short  short8 __attribute__((ext_vector_type(8)));
typedef short  short4v __attribute__((ext_vector_type(4)));

// fp32 -> bf16 bits, round-to-nearest-even
__device__ inline short f2bf(float f) {
    unsigned u = __builtin_bit_cast(unsigned, f);
    u += 0x7fffu + ((u >> 16) & 1u);
    return (short)(u >> 16);
}

// ---------------------------------------------------------------------------
// Kernel 1: h = node_feats @ Wn.T + bn  (fp32, exact)
//           out = relu(h + res_w) / degs   (residual path init)
//           h stored to workspace for the edge kernel's gather.
// 16 rows per block (256 threads, each thread: 1 col x 8 rows).
// ---------------------------------------------------------------------------
__global__ __launch_bounds__(256) void node_kernel(
    const float* __restrict__ nf, const float* __restrict__ degs,
    const float* __restrict__ Wn, const float* __restrict__ bn,
    const float* __restrict__ res_w, float* __restrict__ h_ws,
    float* __restrict__ out)
{
    __shared__ float sm[16 * D];
    const int t = threadIdx.x;
    const int base = blockIdx.x * 16;

    // stage 16 node rows (coalesced)
    #pragma unroll
    for (int i = 0; i < 8; ++i) sm[t + i * 256] = nf[base * D + t + i * 256];
    __syncthreads();

    const int j = t & 127;            // output column
    const int rbase = (t >> 7) * 8;   // 8 rows per thread

    float acc[8];
    const float b = bn[j];
    #pragma unroll
    for (int r = 0; r < 8; ++r) acc[r] = b;

    const float* wrow = Wn + j * D;   // Wn[j][k], contiguous
    #pragma unroll 4
    for (int k = 0; k < D; k += 4) {
        const float4 w = *(const float4*)(wrow + k);
        #pragma unroll
        for (int r = 0; r < 8; ++r) {
            const float* s = &sm[(rbase + r) * D + k];
            acc[r] += s[0] * w.x + s[1] * w.y + s[2] * w.z + s[3] * w.w;
        }
    }

    const float rw = res_w[j];
    #pragma unroll
    for (int r = 0; r < 8; ++r) {
        const int row = base + rbase + r;
        const float h = acc[r];
        h_ws[row * D + j] = h;
        out[row * D + j] = fmaxf(h + rw, 0.0f) / degs[row];
    }
}

// ---------------------------------------------------------------------------
// Kernel 2: per edge tile (128 edges/block, 32 edges/wave):
//   e    = edge_feats @ We.T + be           (bf16 MFMA 16x16x32, fp32 acc)
//   msg  = norm * relu(h[src] + e)
//   out[dst] += msg                          (atomicAdd f32)
// We staged in LDS as bf16 once per block; edge rows held in registers.
// ---------------------------------------------------------------------------
constexpr int WE_PAD = 8;                 // +8 bf16 = +16B row pad
constexpr int WE_LD  = D + WE_PAD;        // 136

__global__ __launch_bounds__(256) void edge_kernel(
    const float* __restrict__ ef, const float* __restrict__ norm,
    const int* __restrict__ src, const int* __restrict__ dst,
    const float* __restrict__ We, const float* __restrict__ be,
    const float* __restrict__ h, float* __restrict__ out)
{
    __shared__ short Wlds[D * WE_LD];     // bf16 bits of We[n][k]

    const int t = threadIdx.x;

    // stage We -> LDS bf16 (float4 reads, short4 writes; 16 iters/thread)
    #pragma unroll
    for (int i = t; i < D * D / 4; i += 256) {
        const int e4 = i * 4;
        const int n = e4 >> 7, k = e4 & 127;
        const float4 w = *(const float4*)(We + e4);
        short4v s;
        s[0] = f2bf(w.x); s[1] = f2bf(w.y); s[2] = f2bf(w.z); s[3] = f2bf(w.w);
        *(short4v*)(&Wlds[n * WE_LD + k]) = s;
    }
    __syncthreads();

    const int lane  = t & 63;
    const int quad  = lane >> 4;          // 0..3
    const int row16 = lane & 15;          // 0..15
    const int wave  = t >> 6;             // 0..3
    const int e0 = blockIdx.x * 128 + wave * 32;   // 32 edges per wave

    // ---- Load A fragments (2 m-tiles x 4 k-tiles), fp32 -> bf16, keep in regs
    // a[mt][kt][j] = A[m = row16][k = kt*32 + quad*8 + j]
    short8 afr[2][4];
    #pragma unroll
    for (int mt = 0; mt < 2; ++mt) {
        const float* p = ef + (e0 + mt * 16 + row16) * D + quad * 8;
        #pragma unroll
        for (int kt = 0; kt < 4; ++kt) {
            const float4 x = *(const float4*)(p + kt * 32);
            const float4 y = *(const float4*)(p + kt * 32 + 4);
            short8 a;
            a[0] = f2bf(x.x); a[1] = f2bf(x.y); a[2] = f2bf(x.z); a[3] = f2bf(x.w);
            a[4] = f2bf(y.x); a[5] = f2bf(y.y); a[6] = f2bf(y.z); a[7] = f2bf(y.w);
            afr[mt][kt] = a;
        }
    }

    // ---- Edge metadata, hoisted out of the n-loop (e independent of n0)
    int   sidx[2][4], didx[2][4];
    float nrm[2][4];
    #pragma unroll
    for (int mt = 0; mt < 2; ++mt) {
        #pragma unroll
        for (int r = 0; r < 4; ++r) {
            const int e = e0 + mt * 16 + quad * 4 + r;
            sidx[mt][r] = src[e];
            didx[mt][r] = dst[e];
            nrm[mt][r]  = norm[e];
        }
    }

    // ---- n-loop over output columns, 16 at a time
    for (int n0 = 0; n0 < D; n0 += 16) {
        // b[kt][j] = B[k = kt*32 + quad*8 + j][n = n0 + row16] = We[n][k]
        const short* bp = &Wlds[(n0 + row16) * WE_LD + quad * 8];
        short8 bfr[4];
        #pragma unroll
        for (int kt = 0; kt < 4; ++kt)
            bfr[kt] = *(const short8*)(bp + kt * 32);

        f32x4 acc0 = {0.f, 0.f, 0.f, 0.f};
        f32x4 acc1 = {0.f, 0.f, 0.f, 0.f};
        #pragma unroll
        for (int kt = 0; kt < 4; ++kt) {
            acc0 = __builtin_amdgcn_mfma_f32_16x16x32_bf16(afr[0][kt], bfr[kt], acc0, 0, 0, 0);
            acc1 = __builtin_amdgcn_mfma_f32_16x16x32_bf16(afr[1][kt], bfr[kt], acc1, 0, 0, 0);
        }

        // epilogue: D layout col = lane&15 (n), row m = quad*4 + r
        const int col = n0 + row16;
        const float bev = be[col];
        #pragma unroll
        for (int r = 0; r < 4; ++r) {
            {
                const float e_val = acc0[r] + bev;
                const float hv = h[sidx[0][r] * D + col];
                const float msg = nrm[0][r] * fmaxf(hv + e_val, 0.0f);
                atomicAdd(&out[didx[0][r] * D + col], msg);
            }
            {
                const float e_val = acc1[r] + bev;
                const float hv = h[sidx[1][r] * D + col];
                const float msg = nrm[1][r] * fmaxf(hv + e_val, 0.0f);
                atomicAdd(&out[didx[1][r] * D + col], msg);
            }
        }
    }
}

extern "C" void kernel_launch(void* const* d_in, const int* in_sizes, int n_in,
                              void* d_out, int out_size, void* d_ws, size_t ws_size,
                              hipStream_t stream) {
    const float* node_feats = (const float*)d_in[0];
    const float* edge_feats = (const float*)d_in[1];
    const float* degs       = (const float*)d_in[2];
    const float* norm       = (const float*)d_in[3];
    const int*   src        = (const int*)d_in[4];
    const int*   dst        = (const int*)d_in[5];
    const float* Wn         = (const float*)d_in[6];
    const float* bn         = (const float*)d_in[7];
    const float* We         = (const float*)d_in[8];
    const float* be         = (const float*)d_in[9];
    const float* res_w      = (const float*)d_in[10];

    float* out  = (float*)d_out;
    float* h_ws = (float*)d_ws;   // N*128 fp32 = 10.24 MB

    // Kernel 1 fully writes out (= residual path) and h_ws; kernel 2 then
    // atomically accumulates the aggregation term. Same stream => ordered.
    node_kernel<<<N_NODES / 16, 256, 0, stream>>>(node_feats, degs, Wn, bn, res_w, h_ws, out);
    edge_kernel<<<N_EDGES / 128, 256, 0, stream>>>(edge_feats, norm, src, dst, We, be, h_ws, out);
}

// Round 2
// 651.923 us; speedup vs baseline: 1.0863x; 1.0863x over previous
//
#include <hip/hip_runtime.h>
#include <hip/hip_bf16.h>

// Problem constants (fixed by the reference file).
constexpr int N_NODES = 20000;
constexpr int N_EDGES = 640000;
constexpr int D = 128;          // D_IN == D_OUT == 128

typedef float  f32x4  __attribute__((ext_vector_type(4)));
typedef short  short8 __attribute__((ext_vector_type(8)));
typedef short  short4v __attribute__((ext_vector_type(4)));

// fp32 -> bf16 bits, round-to-nearest-even
__device__ inline short f2bf(float f) {
    unsigned u = __builtin_bit_cast(unsigned, f);
    u += 0x7fffu + ((u >> 16) & 1u);
    return (short)(u >> 16);
}

// ---------------------------------------------------------------------------
// Sort infrastructure: counting sort of edges by dst.
// ---------------------------------------------------------------------------
__global__ __launch_bounds__(256) void hist_kernel(
    const int* __restrict__ dst, int* __restrict__ count)
{
    const int e = blockIdx.x * 256 + threadIdx.x;
    if (e < N_EDGES) atomicAdd(&count[dst[e]], 1);
}

// Single block, 1024 threads: exclusive prefix sum of count[0..N) -> cursor.
__global__ __launch_bounds__(1024) void scan_kernel(
    const int* __restrict__ count, int* __restrict__ cursor)
{
    constexpr int PER = 20;                    // 1024*20 = 20480 >= 20000
    __shared__ int tot[1024];
    const int tid = threadIdx.x;
    const int base = tid * PER;

    int local[PER];
    int s = 0;
    #pragma unroll
    for (int i = 0; i < PER; ++i) {
        const int idx = base + i;
        const int v = (idx < N_NODES) ? count[idx] : 0;
        local[i] = s;                          // exclusive within chunk
        s += v;
    }
    tot[tid] = s;
    __syncthreads();
    // Hillis-Steele inclusive scan over 1024 chunk totals
    for (int off = 1; off < 1024; off <<= 1) {
        const int add = (tid >= off) ? tot[tid - off] : 0;
        __syncthreads();
        tot[tid] += add;
        __syncthreads();
    }
    const int excl = tot[tid] - s;             // exclusive chunk base
    #pragma unroll
    for (int i = 0; i < PER; ++i) {
        const int idx = base + i;
        if (idx < N_NODES) cursor[idx] = excl + local[i];
    }
}

__global__ __launch_bounds__(256) void scatter_kernel(
    const int* __restrict__ dst, int* __restrict__ cursor,
    int* __restrict__ perm, int* __restrict__ dsts)
{
    const int e = blockIdx.x * 256 + threadIdx.x;
    if (e < N_EDGES) {
        const int d = dst[e];
        const int pos = atomicAdd(&cursor[d], 1);
        perm[pos] = e;
        dsts[pos] = d;
    }
}

// ---------------------------------------------------------------------------
// Kernel 1: h = node_feats @ Wn.T + bn  (fp32, exact)
//           out = relu(h + res_w) / degs   (residual path init)
// ---------------------------------------------------------------------------
__global__ __launch_bounds__(256) void node_kernel(
    const float* __restrict__ nf, const float* __restrict__ degs,
    const float* __restrict__ Wn, const float* __restrict__ bn,
    const float* __restrict__ res_w, float* __restrict__ h_ws,
    float* __restrict__ out)
{
    __shared__ float sm[16 * D];
    const int t = threadIdx.x;
    const int base = blockIdx.x * 16;

    #pragma unroll
    for (int i = 0; i < 8; ++i) sm[t + i * 256] = nf[base * D + t + i * 256];
    __syncthreads();

    const int j = t & 127;            // output column
    const int rbase = (t >> 7) * 8;   // 8 rows per thread

    float acc[8];
    const float b = bn[j];
    #pragma unroll
    for (int r = 0; r < 8; ++r) acc[r] = b;

    const float* wrow = Wn + j * D;
    #pragma unroll 4
    for (int k = 0; k < D; k += 4) {
        const float4 w = *(const float4*)(wrow + k);
        #pragma unroll
        for (int r = 0; r < 8; ++r) {
            const float* s = &sm[(rbase + r) * D + k];
            acc[r] += s[0] * w.x + s[1] * w.y + s[2] * w.z + s[3] * w.w;
        }
    }

    const float rw = res_w[j];
    #pragma unroll
    for (int r = 0; r < 8; ++r) {
        const int row = base + rbase + r;
        const float h = acc[r];
        h_ws[row * D + j] = h;
        out[row * D + j] = fmaxf(h + rw, 0.0f) / degs[row];
    }
}

// ---------------------------------------------------------------------------
// Kernel 2: edges processed in dst-sorted order (via perm).
//   e    = edge_feats[perm] @ We.T + be     (bf16 MFMA 16x16x32, fp32 acc)
//   msg  = norm * relu(h[src] + e)
//   segmented sum over sorted-dst runs in LDS; one atomicAdd per run
//   (~12 atomics/edge-row -> ~1 atomic per 2.7 output elements per tile).
// ---------------------------------------------------------------------------
constexpr int WE_PAD = 8;                 // +8 bf16 = +16B row pad
constexpr int WE_LD  = D + WE_PAD;        // 136
constexpr int TILE_LD = 33;               // 32 m-values + 1 pad (floats)

__global__ __launch_bounds__(256) void edge_kernel(
    const float* __restrict__ ef, const float* __restrict__ norm,
    const int* __restrict__ src,
    const int* __restrict__ perm, const int* __restrict__ dsts,
    const float* __restrict__ We, const float* __restrict__ be,
    const float* __restrict__ h, float* __restrict__ out)
{
    __shared__ short Wlds[D * WE_LD];       // 34816 B: bf16 We[n][k]
    __shared__ float tile[4][32 * TILE_LD]; // 16896 B: per-wave [col][m]
    __shared__ int   sdst[4][32];           // 512 B: per-wave sorted dsts

    const int t = threadIdx.x;

    // stage We -> LDS bf16
    #pragma unroll
    for (int i = t; i < D * D / 4; i += 256) {
        const int e4 = i * 4;
        const int n = e4 >> 7, k = e4 & 127;
        const float4 w = *(const float4*)(We + e4);
        short4v s;
        s[0] = f2bf(w.x); s[1] = f2bf(w.y); s[2] = f2bf(w.z); s[3] = f2bf(w.w);
        *(short4v*)(&Wlds[n * WE_LD + k]) = s;
    }

    const int lane  = t & 63;
    const int quad  = lane >> 4;          // 0..3
    const int row16 = lane & 15;          // 0..15
    const int wave  = t >> 6;             // 0..3
    const int p0 = blockIdx.x * 128 + wave * 32;   // 32 sorted positions/wave

    if (lane < 32) sdst[wave][lane] = dsts[p0 + lane];
    __syncthreads();

    // ---- A fragments: gather edge rows via perm, fp32 -> bf16, keep in regs
    short8 afr[2][4];
    #pragma unroll
    for (int mt = 0; mt < 2; ++mt) {
        const int erow = perm[p0 + mt * 16 + row16];
        const float* p = ef + erow * D + quad * 8;
        #pragma unroll
        for (int kt = 0; kt < 4; ++kt) {
            const float4 x = *(const float4*)(p + kt * 32);
            const float4 y = *(const float4*)(p + kt * 32 + 4);
            short8 a;
            a[0] = f2bf(x.x); a[1] = f2bf(x.y); a[2] = f2bf(x.z); a[3] = f2bf(x.w);
            a[4] = f2bf(y.x); a[5] = f2bf(y.y); a[6] = f2bf(y.z); a[7] = f2bf(y.w);
            afr[mt][kt] = a;
        }
    }

    // ---- Edge metadata (src, norm) for epilogue rows this lane owns
    int   sidx[2][4];
    float nrm[2][4];
    #pragma unroll
    for (int mt = 0; mt < 2; ++mt) {
        #pragma unroll
        for (int r = 0; r < 4; ++r) {
            const int pe = perm[p0 + mt * 16 + quad * 4 + r];
            sidx[mt][r] = src[pe];
            nrm[mt][r]  = norm[pe];
        }
    }

    // ---- 4 groups of 2 n-tiles: MFMA + epilogue to LDS, then segmented scan
    for (int g = 0; g < 4; ++g) {
        #pragma unroll
        for (int t2 = 0; t2 < 2; ++t2) {
            const int n0 = g * 32 + t2 * 16;
            const short* bp = &Wlds[(n0 + row16) * WE_LD + quad * 8];
            short8 bfr[4];
            #pragma unroll
            for (int kt = 0; kt < 4; ++kt)
                bfr[kt] = *(const short8*)(bp + kt * 32);

            f32x4 acc0 = {0.f, 0.f, 0.f, 0.f};
            f32x4 acc1 = {0.f, 0.f, 0.f, 0.f};
            #pragma unroll
            for (int kt = 0; kt < 4; ++kt) {
                acc0 = __builtin_amdgcn_mfma_f32_16x16x32_bf16(afr[0][kt], bfr[kt], acc0, 0, 0, 0);
                acc1 = __builtin_amdgcn_mfma_f32_16x16x32_bf16(afr[1][kt], bfr[kt], acc1, 0, 0, 0);
            }

            // epilogue: C/D layout col = lane&15, row m = quad*4 + r
            const int col = n0 + row16;
            const float bev = be[col];
            float* tp = &tile[wave][(t2 * 16 + row16) * TILE_LD];
            #pragma unroll
            for (int r = 0; r < 4; ++r) {
                const int m0 = quad * 4 + r;
                const float hv0 = h[sidx[0][r] * D + col];
                tp[m0] = nrm[0][r] * fmaxf(hv0 + acc0[r] + bev, 0.0f);
                const int m1 = m0 + 16;
                const float hv1 = h[sidx[1][r] * D + col];
                tp[m1] = nrm[1][r] * fmaxf(hv1 + acc1[r] + bev, 0.0f);
            }
        }
        __syncthreads();

        // segmented scan: lane handles col c (of this 32-col group), rows
        // chunk*16 .. chunk*16+15; emit one atomic per dst-run.
        {
            const int c = lane >> 1;
            const int chunk = lane & 1;
            const int mbeg = chunk * 16;
            const float* sp = &tile[wave][c * TILE_LD];
            const int gcol = g * 32 + c;
            int cur = sdst[wave][mbeg];
            float sum = 0.0f;
            #pragma unroll
            for (int m = mbeg; m < mbeg + 16; ++m) {
                const int dm = sdst[wave][m];
                const float v = sp[m];
                if (dm != cur) {
                    atomicAdd(&out[cur * D + gcol], sum);
                    sum = 0.0f;
                    cur = dm;
                }
                sum += v;
            }
            atomicAdd(&out[cur * D + gcol], sum);
        }
        __syncthreads();
    }
}

extern "C" void kernel_launch(void* const* d_in, const int* in_sizes, int n_in,
                              void* d_out, int out_size, void* d_ws, size_t ws_size,
                              hipStream_t stream) {
    const float* node_feats = (const float*)d_in[0];
    const float* edge_feats = (const float*)d_in[1];
    const float* degs       = (const float*)d_in[2];
    const float* norm       = (const float*)d_in[3];
    const int*   src        = (const int*)d_in[4];
    const int*   dst        = (const int*)d_in[5];
    const float* Wn         = (const float*)d_in[6];
    const float* bn         = (const float*)d_in[7];
    const float* We         = (const float*)d_in[8];
    const float* be         = (const float*)d_in[9];
    const float* res_w      = (const float*)d_in[10];

    float* out = (float*)d_out;

    // Workspace layout (bytes):
    //   h:      [0,        10240000)   N*D fp32
    //   perm:   [10240000, 12800000)   E i32
    //   dsts:   [12800000, 15360000)   E i32
    //   count:  [15360000, 15440000)   N i32 (doubles as scatter cursor)
    char* ws = (char*)d_ws;
    float* h_ws  = (float*)(ws);
    int*   perm  = (int*)(ws + 10240000);
    int*   dsts  = (int*)(ws + 12800000);
    int*   count = (int*)(ws + 15360000);

    // 1) counting sort of edges by dst
    hipMemsetAsync(count, 0, N_NODES * sizeof(int), stream);
    hist_kernel<<<(N_EDGES + 255) / 256, 256, 0, stream>>>(dst, count);
    scan_kernel<<<1, 1024, 0, stream>>>(count, count);   // in-place excl scan
    scatter_kernel<<<(N_EDGES + 255) / 256, 256, 0, stream>>>(dst, count, perm, dsts);

    // 2) node path: writes h and the residual term into out
    node_kernel<<<N_NODES / 16, 256, 0, stream>>>(node_feats, degs, Wn, bn, res_w, h_ws, out);

    // 3) edge path: sorted-order GEMM + segmented-sum aggregation
    edge_kernel<<<N_EDGES / 128, 256, 0, stream>>>(edge_feats, norm, src, perm, dsts,
                                                   We, be, h_ws, out);
}

// Round 3
// 632.542 us; speedup vs baseline: 1.1196x; 1.0306x over previous
//
#include <hip/hip_runtime.h>
#include <hip/hip_bf16.h>

// Problem constants (fixed by the reference file).
constexpr int N_NODES = 20000;
constexpr int N_EDGES = 640000;
constexpr int D = 128;          // D_IN == D_OUT == 128

typedef float  f32x4  __attribute__((ext_vector_type(4)));
typedef short  short8 __attribute__((ext_vector_type(8)));

// fp32 -> bf16 bits, round-to-nearest-even
__device__ inline short f2bf(float f) {
    unsigned u = __builtin_bit_cast(unsigned, f);
    u += 0x7fffu + ((u >> 16) & 1u);
    return (short)(u >> 16);
}
__device__ inline float bf2f(short s) {
    unsigned u = ((unsigned)(unsigned short)s) << 16;
    return __builtin_bit_cast(float, u);
}

// ---------------------------------------------------------------------------
// Prep: convert W (128x128, row-major W[n][k]) into MFMA B-fragment-major
// bf16 arrays.  Fragment index: frag[(nt*4 + kt)*64 + lane], lane = quad*16 +
// row16, holding W[nt*16 + row16][kt*32 + quad*8 + j] for j=0..7.  A wave
// then loads its B fragment for (nt,kt) as one coalesced 16B/lane read.
// We -> fragE (plain bf16).  Wn -> fragH/fragL (hi/lo split for ~fp32 h).
// ---------------------------------------------------------------------------
__global__ __launch_bounds__(256) void prep_kernel(
    const float* __restrict__ We, const float* __restrict__ Wn,
    short8* __restrict__ fragE, short8* __restrict__ fragH,
    short8* __restrict__ fragL)
{
    const int t = blockIdx.x * 256 + threadIdx.x;   // 2048 threads, 1 chunk each
    const int n = t >> 4, k8 = t & 15;              // chunk = row n, 8-col group k8
    const int kt = k8 >> 2, q = k8 & 3;
    const int fi = ((n >> 4) * 4 + kt) * 64 + q * 16 + (n & 15);

    {
        const float4 x = *(const float4*)(We + n * D + k8 * 8);
        const float4 y = *(const float4*)(We + n * D + k8 * 8 + 4);
        const float v[8] = {x.x, x.y, x.z, x.w, y.x, y.y, y.z, y.w};
        short8 s;
        #pragma unroll
        for (int j = 0; j < 8; ++j) s[j] = f2bf(v[j]);
        fragE[fi] = s;
    }
    {
        const float4 x = *(const float4*)(Wn + n * D + k8 * 8);
        const float4 y = *(const float4*)(Wn + n * D + k8 * 8 + 4);
        const float v[8] = {x.x, x.y, x.z, x.w, y.x, y.y, y.z, y.w};
        short8 hi, lo;
        #pragma unroll
        for (int j = 0; j < 8; ++j) {
            hi[j] = f2bf(v[j]);
            lo[j] = f2bf(v[j] - bf2f(hi[j]));
        }
        fragH[fi] = hi;
        fragL[fi] = lo;
    }
}

// ---------------------------------------------------------------------------
// Sort infrastructure: counting sort of edges by dst.
// ---------------------------------------------------------------------------
__global__ __launch_bounds__(256) void hist_kernel(
    const int* __restrict__ dst, int* __restrict__ count)
{
    const int e = blockIdx.x * 256 + threadIdx.x;
    if (e < N_EDGES) atomicAdd(&count[dst[e]], 1);
}

__global__ __launch_bounds__(1024) void scan_kernel(
    const int* __restrict__ count, int* __restrict__ cursor)
{
    constexpr int PER = 20;                    // 1024*20 = 20480 >= 20000
    __shared__ int tot[1024];
    const int tid = threadIdx.x;
    const int base = tid * PER;

    int local[PER];
    int s = 0;
    #pragma unroll
    for (int i = 0; i < PER; ++i) {
        const int idx = base + i;
        const int v = (idx < N_NODES) ? count[idx] : 0;
        local[i] = s;
        s += v;
    }
    tot[tid] = s;
    __syncthreads();
    for (int off = 1; off < 1024; off <<= 1) {
        const int add = (tid >= off) ? tot[tid - off] : 0;
        __syncthreads();
        tot[tid] += add;
        __syncthreads();
    }
    const int excl = tot[tid] - s;
    #pragma unroll
    for (int i = 0; i < PER; ++i) {
        const int idx = base + i;
        if (idx < N_NODES) cursor[idx] = excl + local[i];
    }
}

__global__ __launch_bounds__(256) void scatter_kernel(
    const int* __restrict__ dst, int* __restrict__ cursor,
    int* __restrict__ perm, int* __restrict__ dsts)
{
    const int e = blockIdx.x * 256 + threadIdx.x;
    if (e < N_EDGES) {
        const int d = dst[e];
        const int pos = atomicAdd(&cursor[d], 1);
        perm[pos] = e;
        dsts[pos] = d;
    }
}

// ---------------------------------------------------------------------------
// Kernel 1: h = nf @ Wn.T + bn via MFMA with bf16 hi/lo split (~fp32 exact):
//   nf = ah + al,  Wn = bh + bl;  acc = ah*bh + ah*bl + al*bh  (al*bl ~ 2^-18)
//   out = relu(h + res_w) / degs  (residual init);  h -> workspace.
// 64 rows/block (4 waves x 16 rows), B fragments from global fragH/fragL.
// ---------------------------------------------------------------------------
__global__ __launch_bounds__(256) void node_kernel(
    const float* __restrict__ nf, const float* __restrict__ degs,
    const short8* __restrict__ fragH, const short8* __restrict__ fragL,
    const float* __restrict__ bn, const float* __restrict__ res_w,
    float* __restrict__ h_ws, float* __restrict__ out)
{
    const int t = threadIdx.x;
    const int lane = t & 63, wave = t >> 6;
    const int quad = lane >> 4, row16 = lane & 15;
    const int mbase = blockIdx.x * 64 + wave * 16;

    // A fragments (hi/lo), row = mbase + row16
    const int arow = min(mbase + row16, N_NODES - 1);
    short8 ah[4], al[4];
    const float* p = nf + arow * D + quad * 8;
    #pragma unroll
    for (int kt = 0; kt < 4; ++kt) {
        const float4 x = *(const float4*)(p + kt * 32);
        const float4 y = *(const float4*)(p + kt * 32 + 4);
        const float v[8] = {x.x, x.y, x.z, x.w, y.x, y.y, y.z, y.w};
        #pragma unroll
        for (int j = 0; j < 8; ++j) {
            ah[kt][j] = f2bf(v[j]);
            al[kt][j] = f2bf(v[j] - bf2f(ah[kt][j]));
        }
    }

    // output rows this lane owns in the epilogue
    int   orow[4];
    float dinv[4];
    #pragma unroll
    for (int r = 0; r < 4; ++r) {
        orow[r] = mbase + quad * 4 + r;
        dinv[r] = 1.0f / degs[min(orow[r], N_NODES - 1)];
    }

    #pragma unroll
    for (int nt = 0; nt < 8; ++nt) {
        f32x4 acc = {0.f, 0.f, 0.f, 0.f};
        #pragma unroll
        for (int kt = 0; kt < 4; ++kt) {
            const short8 bh = fragH[(nt * 4 + kt) * 64 + lane];
            const short8 bl = fragL[(nt * 4 + kt) * 64 + lane];
            acc = __builtin_amdgcn_mfma_f32_16x16x32_bf16(al[kt], bh, acc, 0, 0, 0);
            acc = __builtin_amdgcn_mfma_f32_16x16x32_bf16(ah[kt], bl, acc, 0, 0, 0);
            acc = __builtin_amdgcn_mfma_f32_16x16x32_bf16(ah[kt], bh, acc, 0, 0, 0);
        }
        const int col = nt * 16 + row16;
        const float bnv = bn[col], rwv = res_w[col];
        #pragma unroll
        for (int r = 0; r < 4; ++r) {
            if (orow[r] < N_NODES) {
                const float h = acc[r] + bnv;
                h_ws[orow[r] * D + col] = h;
                out[orow[r] * D + col] = fmaxf(h + rwv, 0.0f) * dinv[r];
            }
        }
    }
}

// ---------------------------------------------------------------------------
// Kernel 2: edges in dst-sorted order (perm).
//   e   = ef[perm] @ We.T + be   (bf16 MFMA, B-fragments from global fragE)
//   msg = norm * relu(h[src] + e)
//   segmented sum over sorted-dst runs (per-wave LDS tile); one atomic/run.
// LDS = 17.4 KB -> ~6 blocks/CU (was 52 KB / 3 blocks).
// ---------------------------------------------------------------------------
constexpr int TILE_LD = 33;               // 32 m + 1 pad: conflict-free both ways

__global__ __launch_bounds__(256) void edge_kernel(
    const float* __restrict__ ef, const float* __restrict__ norm,
    const int* __restrict__ src,
    const int* __restrict__ perm, const int* __restrict__ dsts,
    const short8* __restrict__ fragE, const float* __restrict__ be,
    const float* __restrict__ h, float* __restrict__ out)
{
    __shared__ float tile[4][32 * TILE_LD]; // 16896 B: per-wave [col][m]
    __shared__ int   sdst[4][32];           // 512 B

    const int t = threadIdx.x;
    const int lane  = t & 63;
    const int quad  = lane >> 4;
    const int row16 = lane & 15;
    const int wave  = t >> 6;
    const int p0 = blockIdx.x * 128 + wave * 32;   // 32 sorted positions/wave

    if (lane < 32) sdst[wave][lane] = dsts[p0 + lane];

    // ---- A fragments: gather edge rows via perm, fp32 -> bf16, keep in regs
    short8 afr[2][4];
    #pragma unroll
    for (int mt = 0; mt < 2; ++mt) {
        const int erow = perm[p0 + mt * 16 + row16];
        const float* p = ef + erow * D + quad * 8;
        #pragma unroll
        for (int kt = 0; kt < 4; ++kt) {
            const float4 x = *(const float4*)(p + kt * 32);
            const float4 y = *(const float4*)(p + kt * 32 + 4);
            short8 a;
            a[0] = f2bf(x.x); a[1] = f2bf(x.y); a[2] = f2bf(x.z); a[3] = f2bf(x.w);
            a[4] = f2bf(y.x); a[5] = f2bf(y.y); a[6] = f2bf(y.z); a[7] = f2bf(y.w);
            afr[mt][kt] = a;
        }
    }

    // ---- Edge metadata (src, norm) for epilogue rows this lane owns
    int   sidx[2][4];
    float nrm[2][4];
    #pragma unroll
    for (int mt = 0; mt < 2; ++mt) {
        #pragma unroll
        for (int r = 0; r < 4; ++r) {
            const int pe = perm[p0 + mt * 16 + quad * 4 + r];
            sidx[mt][r] = src[pe];
            nrm[mt][r]  = norm[pe];
        }
    }
    __syncthreads();   // sdst visibility

    // ---- 4 groups of 2 n-tiles: MFMA + epilogue to LDS, then segmented scan
    for (int g = 0; g < 4; ++g) {
        #pragma unroll
        for (int t2 = 0; t2 < 2; ++t2) {
            const int nt = g * 2 + t2;
            short8 bfr[4];
            #pragma unroll
            for (int kt = 0; kt < 4; ++kt)
                bfr[kt] = fragE[(nt * 4 + kt) * 64 + lane];

            f32x4 acc0 = {0.f, 0.f, 0.f, 0.f};
            f32x4 acc1 = {0.f, 0.f, 0.f, 0.f};
            #pragma unroll
            for (int kt = 0; kt < 4; ++kt) {
                acc0 = __builtin_amdgcn_mfma_f32_16x16x32_bf16(afr[0][kt], bfr[kt], acc0, 0, 0, 0);
                acc1 = __builtin_amdgcn_mfma_f32_16x16x32_bf16(afr[1][kt], bfr[kt], acc1, 0, 0, 0);
            }

            // epilogue: C/D layout col = lane&15, row m = quad*4 + r
            const int col = nt * 16 + row16;
            const float bev = be[col];
            float* tp = &tile[wave][(t2 * 16 + row16) * TILE_LD];
            #pragma unroll
            for (int r = 0; r < 4; ++r) {
                const int m0 = quad * 4 + r;
                const float hv0 = h[sidx[0][r] * D + col];
                tp[m0] = nrm[0][r] * fmaxf(hv0 + acc0[r] + bev, 0.0f);
                const int m1 = m0 + 16;
                const float hv1 = h[sidx[1][r] * D + col];
                tp[m1] = nrm[1][r] * fmaxf(hv1 + acc1[r] + bev, 0.0f);
            }
        }
        __syncthreads();

        // segmented scan: lane = col*2 + chunk; chunk covers 16 sorted rows.
        {
            const int c = lane >> 1;
            const int chunk = lane & 1;
            const int mbeg = chunk * 16;
            const float* sp = &tile[wave][c * TILE_LD];
            const int gcol = g * 32 + c;
            int cur = sdst[wave][mbeg];
            float sum = 0.0f;
            #pragma unroll
            for (int m = mbeg; m < mbeg + 16; ++m) {
                const int dm = sdst[wave][m];
                const float v = sp[m];
                if (dm != cur) {
                    atomicAdd(&out[cur * D + gcol], sum);
                    sum = 0.0f;
                    cur = dm;
                }
                sum += v;
            }
            atomicAdd(&out[cur * D + gcol], sum);
        }
        __syncthreads();
    }
}

extern "C" void kernel_launch(void* const* d_in, const int* in_sizes, int n_in,
                              void* d_out, int out_size, void* d_ws, size_t ws_size,
                              hipStream_t stream) {
    const float* node_feats = (const float*)d_in[0];
    const float* edge_feats = (const float*)d_in[1];
    const float* degs       = (const float*)d_in[2];
    const float* norm       = (const float*)d_in[3];
    const int*   src        = (const int*)d_in[4];
    const int*   dst        = (const int*)d_in[5];
    const float* Wn         = (const float*)d_in[6];
    const float* bn         = (const float*)d_in[7];
    const float* We         = (const float*)d_in[8];
    const float* be         = (const float*)d_in[9];
    const float* res_w      = (const float*)d_in[10];

    float* out = (float*)d_out;

    // Workspace layout (bytes):
    //   h:      [0,        10240000)   N*D fp32
    //   perm:   [10240000, 12800000)   E i32
    //   dsts:   [12800000, 15360000)   E i32
    //   count:  [15360000, 15440000)   N i32 (doubles as scatter cursor)
    //   fragE:  [15500000, +32768)     We bf16 fragments
    //   fragH:  [15600000, +32768)     Wn hi fragments
    //   fragL:  [15700000, +32768)     Wn lo fragments
    char* ws = (char*)d_ws;
    float*  h_ws  = (float*)(ws);
    int*    perm  = (int*)(ws + 10240000);
    int*    dsts  = (int*)(ws + 12800000);
    int*    count = (int*)(ws + 15360000);
    short8* fragE = (short8*)(ws + 15500000);
    short8* fragH = (short8*)(ws + 15600000);
    short8* fragL = (short8*)(ws + 15700000);

    // 0) weight fragments
    prep_kernel<<<8, 256, 0, stream>>>(We, Wn, fragE, fragH, fragL);

    // 1) counting sort of edges by dst
    hipMemsetAsync(count, 0, N_NODES * sizeof(int), stream);
    hist_kernel<<<(N_EDGES + 255) / 256, 256, 0, stream>>>(dst, count);
    scan_kernel<<<1, 1024, 0, stream>>>(count, count);
    scatter_kernel<<<(N_EDGES + 255) / 256, 256, 0, stream>>>(dst, count, perm, dsts);

    // 2) node path: writes h and the residual term into out
    node_kernel<<<(N_NODES + 63) / 64, 256, 0, stream>>>(node_feats, degs, fragH, fragL,
                                                         bn, res_w, h_ws, out);

    // 3) edge path: sorted-order GEMM + segmented-sum aggregation
    edge_kernel<<<N_EDGES / 128, 256, 0, stream>>>(edge_feats, norm, src, perm, dsts,
                                                   fragE, be, h_ws, out);
}